// Round 6
// baseline (114.874 us; speedup 1.0000x reference)
//
#include <hip/hip_runtime.h>

#define L2E 1.4426950408889634f
#define LN2 0.6931471805599453f

typedef float f32x16 __attribute__((ext_vector_type(16)));
typedef float f32x2  __attribute__((ext_vector_type(2)));
typedef short bf16x8 __attribute__((ext_vector_type(8)));
typedef unsigned int u32x4 __attribute__((ext_vector_type(4)));

__device__ __forceinline__ float dexp2(float x) { return __builtin_amdgcn_exp2f(x); }
__device__ __forceinline__ float dlog2(float x) { return __builtin_amdgcn_logf(x); }

// HW packed f32->2xbf16 (RNE). Inputs must be IR-produced VALU values
// (never raw MFMA accumulator regs) -- R3 post-mortem.
__device__ __forceinline__ unsigned cvtpk(float a, float b) {
    unsigned r;
    asm("v_cvt_pk_bf16_f32 %0, %1, %2" : "=v"(r) : "v"(a), "v"(b));
    return r;
}

// Software RNE pack (pure IR): for cold paths reading raw MFMA results.
__device__ __forceinline__ unsigned pkrne(float a, float b) {
    unsigned ua = __float_as_uint(a), ub = __float_as_uint(b);
    ua += 0x7FFFu + ((ua >> 16) & 1u);
    ub += 0x7FFFu + ((ub >> 16) & 1u);
    return __builtin_amdgcn_perm(ub, ua, 0x07060302u);
}

// CRF forward via exp-domain transfer matrices, C-form chain:
//   tau_t = E * (D_t * tau_{t-1}),  tau_0 = E[:,START]
// A-operand = E is CONSTANT (bf16, packed once). D_t is a B-side row scale
// fused into the per-step acc->bf16 pack. 1 WG (16 waves, 1024 thr) per
// batch; each wave builds ONE 128-step chunk matrix -> 8 waves/SIMD
// occupancy (R5 was latency-bound at 4). Phase 2 chains 16 chunk matrices.
__global__ __launch_bounds__(1024, 8) void crf_phase_kernel(
    const float* __restrict__ em,   // [512][2048][32]
    const float* __restrict__ tr,   // [32][32] transitions[tag][prev]
    const int*   __restrict__ tgs,  // [512][2048]
    float*       __restrict__ ws)   // [512] per-batch nll
{
    __shared__ float s_tr[1024];                 // 4 KB
    __shared__ unsigned short s_mat[16 * 1024];  // 32 KB [chunk][col][row] bf16
    __shared__ float s_ring[16 * 256];           // 16 KB [wave][8 slots][32]
    __shared__ float s_base[16];
    __shared__ float s_gold[16];

    const int tid = threadIdx.x;
    const int b   = blockIdx.x;
    const int w   = tid >> 6;    // wave = chunk index 0..15
    const int l   = tid & 63;
    const int h   = l >> 5;
    const int q   = l & 31;

    s_tr[tid & 1023] = tr[tid & 1023];   // 1024 threads, one element each
    __syncthreads();

    // Constant A = E with pi'd columns (pi = swap bits 2<->3), bf16, packed once.
    unsigned ea[8];
#pragma unroll
    for (int j = 0; j < 8; ++j) {
        int k0  = 16 * (j >> 2) + 8 * h + 2 * (j & 3);
        int col = (k0 & ~12) | ((k0 & 4) << 1) | ((k0 & 8) >> 1);
        ea[j] = pkrne(dexp2(s_tr[q * 32 + col] * L2E),
                      dexp2(s_tr[q * 32 + col + 1] * L2E));
    }
    const bf16x8 A0 = __builtin_bit_cast(bf16x8, (u32x4){ea[0], ea[1], ea[2], ea[3]});
    const bf16x8 A1 = __builtin_bit_cast(bf16x8, (u32x4){ea[4], ea[5], ea[6], ea[7]});

    f32x16 zro;
#pragma unroll
    for (int z = 0; z < 16; ++z) zro[z] = 0.f;

    const float* ebase = em + ((size_t)b * 2048 + (size_t)w * 128) * 32;
    const int*   tgp   = tgs + (size_t)b * 2048;
    float*       ring  = s_ring + w * 256;

    f32x16 acc;              // carried chunk product (f32, C/D layout)
    float  s_cur = 1.f;      // pending 2^-k rescale (applied at s==0/s==4 packs)
    int    k_pend = 0, sigma = 0;
    float  gold = 0.f;
    float4 r0, r1;
    int    tregC = 0, tlastC = 0, tregN = 0, tlastN = 0;

    // identity product (f32, C/D layout)
#pragma unroll
    for (int r = 0; r < 16; ++r)
        acc[r] = ((((r & 3) + 8 * (r >> 2) + 4 * h) == q) ? 1.f : 0.f);

    auto eload = [&](int blk) -> float4 {
        int bb2 = blk > 15 ? 15 : blk;
        return *(const float4*)(ebase + ((bb2 * 8 + (l >> 3)) * 32 + (l & 7) * 4));
    };
    auto tagload = [&](int cl, int& treg, int& tlast) {
        int c0 = w * 128 + cl * 64;
        int idx = c0 - 1 + l; if (idx < 0) idx = 0;
        treg  = tgp[idx];
        tlast = tgp[c0 + 63];
    };

    r0 = eload(0); r1 = eload(1);
    tagload(0, tregC, tlastC);

#pragma unroll 1
    for (int blk = 0; blk < 16; ++blk) {
        if ((blk & 7) == 0) {
            int cl = blk >> 3;           // 0 or 1
            int cg = w * 2 + cl;         // global 64-group index 0..31
            if (cl > 0) { tregC = tregN; tlastC = tlastN; }
            {   // gold transition terms for this 64-group
                int scur = __shfl(tregC, (l + 1) & 63, 64);
                int cur  = (l == 63) ? tlastC : scur;
                int prev = tregC;
                if (l == 0 && cg == 0) prev = 30;      // START
                gold += s_tr[cur * 32 + prev];
            }
            if (cl < 1) tagload(cl + 1, tregN, tlastN);
        }

        // ---- stage d_t = exp(e_t): gold pick + exp2 -> ring ----
        {
            int trel = (blk & 7) * 8 + (l >> 3);
            int tshf = __shfl(tregC, (trel + 1) & 63, 64);
            int tgt  = (trel == 63) ? tlastC : tshf;
            if ((tgt >> 2) == (l & 7)) {
                int sub = tgt & 3;
                float ev = sub == 0 ? r0.x : sub == 1 ? r0.y : sub == 2 ? r0.z : r0.w;
                gold += ev;
            }
            float4 dv;
            dv.x = dexp2(r0.x * L2E); dv.y = dexp2(r0.y * L2E);
            dv.z = dexp2(r0.z * L2E); dv.w = dexp2(r0.w * L2E);
            *(float4*)(ring + (l >> 3) * 32 + (l & 7) * 4) = dv;
        }
        r0 = r1; r1 = eload(blk + 2);

        const bool skiplast = (blk == 15) && (w == 15);  // global step 2048

        // ---- 8 steps: acc <- E * (d_t o (s*acc)) ; A constant ----
#pragma unroll
        for (int s = 0; s < 8; ++s) {
            if (s == 7 && skiplast) continue;
            const float4* rp = (const float4*)(ring + s * 32 + h * 4);
            unsigned bbn[8];
#pragma unroll
            for (int q2 = 0; q2 < 4; ++q2) {
                float4 d4 = rp[q2 * 2];   // d[8q2+4h .. +3], broadcast per half
                f32x2 a0; a0.x = acc[4 * q2 + 0]; a0.y = acc[4 * q2 + 1];
                f32x2 d0; d0.x = d4.x; d0.y = d4.y;
                f32x2 m0 = a0 * d0;
                f32x2 a1; a1.x = acc[4 * q2 + 2]; a1.y = acc[4 * q2 + 3];
                f32x2 d1; d1.x = d4.z; d1.y = d4.w;
                f32x2 m1 = a1 * d1;
                if (s == 0 || s == 4) {
                    f32x2 sc; sc.x = s_cur; sc.y = s_cur;
                    m0 = m0 * sc; m1 = m1 * sc;
                }
                bbn[2 * q2]     = cvtpk(m0.x, m0.y);
                bbn[2 * q2 + 1] = cvtpk(m1.x, m1.y);
            }
            if (s == 0 || s == 4) sigma += k_pend;
            bf16x8 B0 = __builtin_bit_cast(bf16x8, (u32x4){bbn[0], bbn[1], bbn[2], bbn[3]});
            bf16x8 B1 = __builtin_bit_cast(bf16x8, (u32x4){bbn[4], bbn[5], bbn[6], bbn[7]});
            f32x16 t = __builtin_amdgcn_mfma_f32_32x32x16_bf16(A0, B0, zro, 0, 0, 0);
            acc = __builtin_amdgcn_mfma_f32_32x32x16_bf16(A1, B1, t, 0, 0, 0);
            if (s == 3 || s == 7) {
                unsigned eb = (__float_as_uint(acc[0]) >> 23) & 0xFF;
                unsigned ku = (unsigned)__builtin_amdgcn_readfirstlane((int)eb);
                k_pend = (int)ku - 127;
                s_cur = __uint_as_float((254u - ku) << 23);
            }
        }
    }

    // ---- store this wave's chunk matrix ----
#pragma unroll
    for (int p = 0; p < 8; ++p) {
        int rrow = ((2 * p) & 3) + 8 * ((2 * p) >> 2) + 4 * h;
        *(unsigned*)(s_mat + w * 1024 + q * 32 + rrow) =
            pkrne(acc[2 * p], acc[2 * p + 1]);
    }
    if (l == 0) s_base[w] = (float)sigma;

    // per-wave gold reduction
#pragma unroll
    for (int m = 1; m < 64; m <<= 1) gold += __shfl_xor(gold, m, 64);
    if (l == 0) s_gold[w] = gold;
    __syncthreads();

    // ---- phase 2: serial chain over 16 chunk matrices (lanes 0..31) ----
    if (tid < 32) {
        int i = tid;
        float x  = dexp2(s_tr[i * 32 + 30] * L2E);   // tau_0 = E[:,START]
        float xb = 0.f, bs = 0.f;
        for (int c = 0; c < 16; ++c) {
            s_ring[i] = x;
            float yv[32];
#pragma unroll
            for (int j = 0; j < 8; ++j) *(float4*)&yv[4 * j] = *(const float4*)&s_ring[4 * j];
            float a2 = 0.f;
#pragma unroll
            for (int j = 0; j < 32; ++j) {
                unsigned short uv = s_mat[c * 1024 + j * 32 + i];
                a2 += __uint_as_float((unsigned)uv << 16) * yv[j];
            }
            unsigned eb2 = (__float_as_uint(a2) >> 23) & 0xFF;
            int ku0 = __shfl((int)eb2, 0, 32);
            x  = a2 * __uint_as_float((unsigned)(254 - ku0) << 23);
            xb += (float)(ku0 - 127);
            bs += s_base[c];
        }
        // final: Z = sum_i exp(tr[STOP,i] + e_2048[i]) * tau_2047[i]
        float elast = em[((size_t)b * 2048 + 2047) * 32 + i];
        float wv = dexp2((s_tr[31 * 32 + i] + elast) * L2E);
        float sv = x * wv;
#pragma unroll
        for (int m2 = 1; m2 < 32; m2 <<= 1) sv += __shfl_xor(sv, m2, 32);
        float logZ = (xb + bs + dlog2(sv)) * LN2;
        if (i == 0) {
            float g = 0.f;
#pragma unroll
            for (int wv2 = 0; wv2 < 16; ++wv2) g += s_gold[wv2];
            g += s_tr[31 * 32 + tgp[2047]];   // STOP term
            ws[b] = logZ - g;
        }
    }
}

// Deterministic fixed-order reduction of the 512 per-batch values.
__global__ __launch_bounds__(64) void crf_reduce_kernel(
    const float* __restrict__ ws, float* __restrict__ out)
{
    int l = threadIdx.x;
    float s = 0.f;
#pragma unroll
    for (int k = 0; k < 8; ++k) s += ws[l + k * 64];
    s += __shfl_xor(s, 1, 64);
    s += __shfl_xor(s, 2, 64);
    s += __shfl_xor(s, 4, 64);
    s += __shfl_xor(s, 8, 64);
    s += __shfl_xor(s, 16, 64);
    s += __shfl_xor(s, 32, 64);
    if (l == 0) out[0] = s;
}

extern "C" void kernel_launch(void* const* d_in, const int* in_sizes, int n_in,
                              void* d_out, int out_size, void* d_ws, size_t ws_size,
                              hipStream_t stream)
{
    const float* em = (const float*)d_in[0];
    const float* tr = (const float*)d_in[1];
    const int*   tg = (const int*)d_in[2];
    float* ws  = (float*)d_ws;
    float* out = (float*)d_out;

    hipLaunchKernelGGL(crf_phase_kernel, dim3(512), dim3(1024), 0, stream, em, tr, tg, ws);
    hipLaunchKernelGGL(crf_reduce_kernel, dim3(1), dim3(64), 0, stream, ws, out);
}